// Round 4
// baseline (8702.477 us; speedup 1.0000x reference)
//
#include <hip/hip_runtime.h>
#include <hip/hip_fp16.h>

#define BATCH 64
#define TSEQ  2048
#define FEAT  256
#define HID   256
#define G4    1024   // 4*HID

typedef _Float16 half2_t __attribute__((ext_vector_type(2)));

__device__ __forceinline__ float dot2acc_u(unsigned int a, unsigned int b, float acc) {
    half2_t ah = __builtin_bit_cast(half2_t, a);
    half2_t bh = __builtin_bit_cast(half2_t, b);
#if __has_builtin(__builtin_amdgcn_fdot2)
    return __builtin_amdgcn_fdot2(ah, bh, acc, false);
#else
    return acc + (float)ah.x * (float)bh.x + (float)ah.y * (float)bh.y;
#endif
}

__device__ __forceinline__ float sig_f(float x)  { return 1.f / (1.f + __expf(-x)); }
__device__ __forceinline__ float tanh_f(float x) { return 1.f - 2.f / (__expf(2.f * x) + 1.f); }

__device__ __forceinline__ unsigned int pack2(float a, float b) {
    half2_t h = { (_Float16)a, (_Float16)b };
    return __builtin_bit_cast(unsigned int, h);
}

// DPP cross-lane add over the 8-lane s-group: 0xB1=xor1, 0x4E=xor2, 0x141=mirror(xor4 in 8).
template <int CTRL>
__device__ __forceinline__ float dpp_add(float x) {
    int y = __builtin_amdgcn_update_dpp(0, __builtin_bit_cast(int, x), CTRL, 0xf, 0xf, true);
    return x + __builtin_bit_cast(float, y);
}

// ---------------- prep: WeightH fp32 [k][j] -> per-block-parity k-split fp16 ----------------
// Block pair {2b,2b+1}: parity P handles global gate cols j = q*256 + P*128 + n, n in [0,128),
// q in {i,f,g,o}; 8 passes of 64 cols: block-local jl = pass*64 + w*8 + c.
// Thread (w,c,s): k-slice = own-half [P*128+16s, +16) (u=0,1) + partner-half
// [(1-P)*128+16s, +16) (u=2,3). Each uint4 = 8 k packed as 4x half2 (k-ascending).
// Layout: WS[((P*8 + pass)*4 + u)*512 + tid].
// Also zeroes the 128 SEQ cells (one per block, 32-uint stride) for the exchange protocol.
__global__ void wt_convert(const float* __restrict__ WH, uint4* __restrict__ WS,
                           unsigned* __restrict__ SEQ) {
    if (blockIdx.x == 0 && threadIdx.x < 128) SEQ[threadIdx.x * 32] = 0;
    int idx = blockIdx.x * 256 + threadIdx.x;   // 32768 total
    int tid = idx & 511;
    int u = (idx >> 9) & 3;
    int pass = (idx >> 11) & 7;
    int parity = (idx >> 14) & 1;
    int w = tid >> 6, c = (tid >> 3) & 7, s = tid & 7;
    int jl = pass * 64 + w * 8 + c;
    int j = (jl >> 7) * 256 + parity * 128 + (jl & 127);
    int half_base = ((u < 2) ? parity : 1 - parity) * 128;
    int k0 = half_base + 16 * s + 8 * (u & 1);
    uint4 v;
    v.x = pack2(WH[(k0 + 0) * G4 + j], WH[(k0 + 1) * G4 + j]);
    v.y = pack2(WH[(k0 + 2) * G4 + j], WH[(k0 + 3) * G4 + j]);
    v.z = pack2(WH[(k0 + 4) * G4 + j], WH[(k0 + 5) * G4 + j]);
    v.w = pack2(WH[(k0 + 6) * G4 + j], WH[(k0 + 7) * G4 + j]);
    WS[((parity * 8 + pass) * 4 + u) * 512 + tid] = v;
}

// ---------------- phase 1: xp = x @ Wx + bx + bh, stored fp16 (unchanged) ----------------
__global__ __launch_bounds__(256) void xproj_gemm(
    const float* __restrict__ X, const float* __restrict__ WX,
    const float* __restrict__ BX, const float* __restrict__ BH,
    _Float16* __restrict__ XP)
{
    __shared__ float As[64][17];
    __shared__ float Bs[16][68];

    const int tid = threadIdx.x;
    const int tx = tid & 15;
    const int ty = tid >> 4;
    const int rowBase = blockIdx.y * 64;
    const int colBase = blockIdx.x * 64;

    const int ea = tid * 4;
    const int ar = ea >> 4, ac = ea & 15;
    const int br = ea >> 6, bc = ea & 63;

    float acc[4][4] = {};

    for (int kt = 0; kt < FEAT; kt += 16) {
        float4 av = *(const float4*)(X  + (size_t)(rowBase + ar) * FEAT + kt + ac);
        float4 bv = *(const float4*)(WX + (size_t)(kt + br) * G4 + colBase + bc);
        As[ar][ac + 0] = av.x; As[ar][ac + 1] = av.y;
        As[ar][ac + 2] = av.z; As[ar][ac + 3] = av.w;
        *(float4*)&Bs[br][bc] = bv;
        __syncthreads();
        #pragma unroll
        for (int kk = 0; kk < 16; ++kk) {
            float4 b = *(const float4*)&Bs[kk][tx * 4];
            float a0 = As[ty * 4 + 0][kk];
            float a1 = As[ty * 4 + 1][kk];
            float a2 = As[ty * 4 + 2][kk];
            float a3 = As[ty * 4 + 3][kk];
            acc[0][0] = fmaf(a0, b.x, acc[0][0]); acc[0][1] = fmaf(a0, b.y, acc[0][1]);
            acc[0][2] = fmaf(a0, b.z, acc[0][2]); acc[0][3] = fmaf(a0, b.w, acc[0][3]);
            acc[1][0] = fmaf(a1, b.x, acc[1][0]); acc[1][1] = fmaf(a1, b.y, acc[1][1]);
            acc[1][2] = fmaf(a1, b.z, acc[1][2]); acc[1][3] = fmaf(a1, b.w, acc[1][3]);
            acc[2][0] = fmaf(a2, b.x, acc[2][0]); acc[2][1] = fmaf(a2, b.y, acc[2][1]);
            acc[2][2] = fmaf(a2, b.z, acc[2][2]); acc[2][3] = fmaf(a2, b.w, acc[2][3]);
            acc[3][0] = fmaf(a3, b.x, acc[3][0]); acc[3][1] = fmaf(a3, b.y, acc[3][1]);
            acc[3][2] = fmaf(a3, b.z, acc[3][2]); acc[3][3] = fmaf(a3, b.w, acc[3][3]);
        }
        __syncthreads();
    }

    const int n0 = colBase + tx * 4;
    float4 bxv = *(const float4*)(BX + n0);
    float4 bhv = *(const float4*)(BH + n0);
    float bb0 = bxv.x + bhv.x, bb1 = bxv.y + bhv.y;
    float bb2 = bxv.z + bhv.z, bb3 = bxv.w + bhv.w;

    #pragma unroll
    for (int i = 0; i < 4; ++i) {
        int row = rowBase + ty * 4 + i;
        _Float16* p = XP + (size_t)row * G4 + n0;
        half2_t p01 = { (_Float16)(acc[i][0] + bb0), (_Float16)(acc[i][1] + bb1) };
        half2_t p23 = { (_Float16)(acc[i][2] + bb2), (_Float16)(acc[i][3] + bb3) };
        *(half2_t*)(p + 0) = p01;
        *(half2_t*)(p + 2) = p23;
    }
}

// ---------------- phase 2: recurrence, 2 blocks (CUs) per batch ----------------
// R3 post-mortem: Occupancy 6.1% = only 64/256 CUs active, and VALUBusy on active
// CUs ~75% => issue-bound per CU. Fix: split each batch's 1024 gate cols across a
// block PAIR (parity P handles n in [P*128, P*128+128) of each gate). Per block:
// 8 passes x 64 cols; weights fully resident (passes 0-3 in LDS 128 KB, passes
// 4-7 in AGPRs 64 regs) -> zero per-step L2 weight traffic. Per step each block
// needs the partner's h-half (256 B): exchanged through LLC with agent-scope
// atomics (relaxed data stores + release seq publish; acquire seq spin + relaxed
// loads), double-buffered by step parity. Mutual dependency bounds skew to 1 step
// so parity slots cannot be overwritten while read. 128 blocks x 130.6 KB LDS =
// 1 block/CU => all co-resident (no spin deadlock). Phase A (own-half k fdot2)
// runs before the spin so the partner's publish latency overlaps compute.
#define DOT8(ACC, H0, H1, W0, W1)                                               \
    ACC = dot2acc_u((H0).x, (W0).x, ACC); ACC = dot2acc_u((H0).y, (W0).y, ACC); \
    ACC = dot2acc_u((H0).z, (W0).z, ACC); ACC = dot2acc_u((H0).w, (W0).w, ACC); \
    ACC = dot2acc_u((H1).x, (W1).x, ACC); ACC = dot2acc_u((H1).y, (W1).y, ACC); \
    ACC = dot2acc_u((H1).z, (W1).z, ACC); ACC = dot2acc_u((H1).w, (W1).w, ACC);

// AGPR -> VGPR readback; loop-variant dummy "s"(t) blocks LICM/CSE (R3-proven).
#define AG_RD(d, a_) asm("v_accvgpr_read_b32 %0, %1" : "=v"(d) : "a"(a_), "s"(t))

#define AG_DOT8(ACC, H0, H1, I0, I1)                                            \
    {                                                                           \
        unsigned q0, q1, q2, q3, q4, q5, q6, q7;                                \
        AG_RD(q0, wa[I0].x); AG_RD(q1, wa[I0].y);                               \
        AG_RD(q2, wa[I0].z); AG_RD(q3, wa[I0].w);                               \
        AG_RD(q4, wa[I1].x); AG_RD(q5, wa[I1].y);                               \
        AG_RD(q6, wa[I1].z); AG_RD(q7, wa[I1].w);                               \
        ACC = dot2acc_u((H0).x, q0, ACC); ACC = dot2acc_u((H0).y, q1, ACC);     \
        ACC = dot2acc_u((H0).z, q2, ACC); ACC = dot2acc_u((H0).w, q3, ACC);     \
        ACC = dot2acc_u((H1).x, q4, ACC); ACC = dot2acc_u((H1).y, q5, ACC);     \
        ACC = dot2acc_u((H1).z, q6, ACC); ACC = dot2acc_u((H1).w, q7, ACC);     \
    }

__global__ __launch_bounds__(512, 2) void lstm_rec(
    const _Float16* __restrict__ XP, const uint4* __restrict__ WS,
    unsigned* __restrict__ EXD, unsigned* __restrict__ SEQ,
    float* __restrict__ OUT)
{
    __shared__ uint4 LDS_W[4 * 4 * 512];                  // passes 0-3, 128 KB
    __shared__ float g_sh[512];                           // 2 KB (block-local gates)
    __shared__ __align__(16) unsigned short hs[256];      // full h, own+partner halves

    const int tid = threadIdx.x;
    const int parity = blockIdx.x & 1;
    const int pair = blockIdx.x >> 1;                     // batch index
    const int w = tid >> 6;
    const int c = (tid >> 3) & 7;
    const int s = tid & 7;

    unsigned* seq_self = SEQ + (pair * 2 + parity) * 32;
    unsigned* seq_par  = SEQ + (pair * 2 + (1 - parity)) * 32;
    unsigned* exd_self = EXD + (pair * 2 + parity) * 2 * 64;
    unsigned* exd_par  = EXD + (pair * 2 + (1 - parity)) * 2 * 64;

    // one-time: passes 4-7 pinned into AGPRs (16 uint4 = 64 regs)
    uint4 wa[16];
    #pragma unroll
    for (int p = 0; p < 4; ++p) {
        #pragma unroll
        for (int u = 0; u < 4; ++u) {
            uint4 v = WS[((parity * 8 + (4 + p)) * 4 + u) * 512 + tid];
            asm("v_accvgpr_write_b32 %0, %1" : "=a"(wa[p * 4 + u].x) : "v"(v.x));
            asm("v_accvgpr_write_b32 %0, %1" : "=a"(wa[p * 4 + u].y) : "v"(v.y));
            asm("v_accvgpr_write_b32 %0, %1" : "=a"(wa[p * 4 + u].z) : "v"(v.z));
            asm("v_accvgpr_write_b32 %0, %1" : "=a"(wa[p * 4 + u].w) : "v"(v.w));
        }
    }
    // one-time: passes 0-3 into LDS (SoA, 16 B stride, conflict-free)
    #pragma unroll
    for (int p = 0; p < 4; ++p) {
        #pragma unroll
        for (int u = 0; u < 4; ++u)
            LDS_W[(p * 4 + u) * 512 + tid] = WS[((parity * 8 + p) * 4 + u) * 512 + tid];
    }

    if (tid < 128) ((unsigned*)hs)[tid] = 0;              // h(-1) = 0, both halves

    const int pbase = parity * 128;
    const _Float16* xpb = XP + (size_t)pair * TSEQ * G4;
    float* outb = OUT + (size_t)pair * TSEQ * HID;

    float c0 = 0.f, c1 = 0.f, hl0 = 0.f, hl1 = 0.f;
    // xp(t=0) for this block's cols: gate q, cols pbase+2e, +1  -> packed half2
    unsigned xv0 = 0, xv1 = 0, xv2 = 0, xv3 = 0;
    if (tid < 64) {
        const _Float16* xq = xpb;
        xv0 = *(const unsigned*)(xq + 0 * 256 + pbase + 2 * tid);
        xv1 = *(const unsigned*)(xq + 1 * 256 + pbase + 2 * tid);
        xv2 = *(const unsigned*)(xq + 2 * 256 + pbase + 2 * tid);
        xv3 = *(const unsigned*)(xq + 3 * 256 + pbase + 2 * tid);
    }
    __syncthreads();

    #pragma unroll 1
    for (int t = 0; t < TSEQ; ++t) {
        // own-half h slice: 32 B = 2x b128 at hs[pbase + 16s .. +16)
        const uint4* hso = (const uint4*)((const char*)hs + parity * 256 + 32 * s);
        uint4 hro0 = hso[0];
        uint4 hro1 = hso[1];

        // next-step xp prefetch (wave 0), issued early to hide HBM latency
        unsigned xn0 = 0, xn1 = 0, xn2 = 0, xn3 = 0;
        if (tid < 64) {
            int tn = (t + 1 < TSEQ) ? (t + 1) : t;
            const _Float16* xq = xpb + (size_t)tn * G4;
            xn0 = *(const unsigned*)(xq + 0 * 256 + pbase + 2 * tid);
            xn1 = *(const unsigned*)(xq + 1 * 256 + pbase + 2 * tid);
            xn2 = *(const unsigned*)(xq + 2 * 256 + pbase + 2 * tid);
            xn3 = *(const unsigned*)(xq + 3 * 256 + pbase + 2 * tid);
        }

        // ---- Phase A: own-half k (overlaps partner's publish latency) ----
        float pacc[8];
        #pragma unroll
        for (int p = 0; p < 4; ++p) {
            uint4 l0 = LDS_W[(p * 4 + 0) * 512 + tid];
            uint4 l1 = LDS_W[(p * 4 + 1) * 512 + tid];
            float a = 0.f;
            DOT8(a, hro0, hro1, l0, l1);
            pacc[p] = a;
        }
        #pragma unroll
        for (int p = 0; p < 4; ++p) {
            float a = 0.f;
            AG_DOT8(a, hro0, hro1, p * 4 + 0, p * 4 + 1);
            pacc[4 + p] = a;
        }

        // ---- fetch partner h(t-1) half (wave 0) ----
        if (tid < 64 && t > 0) {
            while (__hip_atomic_load(seq_par, __ATOMIC_ACQUIRE,
                                     __HIP_MEMORY_SCOPE_AGENT) < (unsigned)t)
                __builtin_amdgcn_s_sleep(1);
            unsigned v = __hip_atomic_load(&exd_par[((t - 1) & 1) * 64 + tid],
                                           __ATOMIC_RELAXED, __HIP_MEMORY_SCOPE_AGENT);
            ((unsigned*)hs)[(1 - parity) * 64 + tid] = v;
        }
        __syncthreads();                                  // B1: partner half ready

        // ---- Phase B: partner-half k ----
        const uint4* hsp = (const uint4*)((const char*)hs + (1 - parity) * 256 + 32 * s);
        uint4 hrp0 = hsp[0];
        uint4 hrp1 = hsp[1];
        #pragma unroll
        for (int p = 0; p < 4; ++p) {
            uint4 l2 = LDS_W[(p * 4 + 2) * 512 + tid];
            uint4 l3 = LDS_W[(p * 4 + 3) * 512 + tid];
            float a = pacc[p];
            DOT8(a, hrp0, hrp1, l2, l3);
            pacc[p] = a;
        }
        #pragma unroll
        for (int p = 0; p < 4; ++p) {
            float a = pacc[4 + p];
            AG_DOT8(a, hrp0, hrp1, p * 4 + 2, p * 4 + 3);
            pacc[4 + p] = a;
        }

        // ---- reduce over the 8 s-lanes, publish block-local gates ----
        #pragma unroll
        for (int p = 0; p < 8; ++p) {
            float a = pacc[p];
            a = dpp_add<0xB1>(a);
            a = dpp_add<0x4E>(a);
            a = dpp_add<0x141>(a);
            if (s == 0) g_sh[p * 64 + w * 8 + c] = a;
        }
        __syncthreads();                                  // B2: gates ready

        // ---- elementwise (wave 0: 64 threads x 2 cols) + exchange publish ----
        if (tid < 64) {
            int e = tid;
            float2 gi = *(float2*)&g_sh[0 * 128 + 2 * e];
            float2 gf = *(float2*)&g_sh[1 * 128 + 2 * e];
            float2 gg = *(float2*)&g_sh[2 * 128 + 2 * e];
            float2 go = *(float2*)&g_sh[3 * 128 + 2 * e];
            half2_t xi = __builtin_bit_cast(half2_t, xv0);
            half2_t xf = __builtin_bit_cast(half2_t, xv1);
            half2_t xg = __builtin_bit_cast(half2_t, xv2);
            half2_t xo = __builtin_bit_cast(half2_t, xv3);
            float i0 = sig_f(gi.x + (float)xi.x),  i1 = sig_f(gi.y + (float)xi.y);
            float f0 = sig_f(gf.x + (float)xf.x),  f1 = sig_f(gf.y + (float)xf.y);
            float g0 = tanh_f(gg.x + (float)xg.x), g1 = tanh_f(gg.y + (float)xg.y);
            float o0 = sig_f(go.x + (float)xo.x),  o1 = sig_f(go.y + (float)xo.y);
            c0 = f0 * c0 + i0 * g0;
            c1 = f1 * c1 + i1 * g1;
            float h0 = o0 * tanh_f(c0);
            float h1 = o1 * tanh_f(c1);
            unsigned hp = pack2(h0, h1);
            // publish first (release drains this wave's stores), then local writes
            __hip_atomic_store(&exd_self[(t & 1) * 64 + e], hp,
                               __ATOMIC_RELAXED, __HIP_MEMORY_SCOPE_AGENT);
            if (e == 0)
                __hip_atomic_store(seq_self, (unsigned)(t + 1),
                                   __ATOMIC_RELEASE, __HIP_MEMORY_SCOPE_AGENT);
            ((unsigned*)hs)[parity * 64 + e] = hp;        // own half for next step
            float2 hv; hv.x = h0; hv.y = h1;
            *(float2*)(outb + (size_t)t * HID + pbase + 2 * e) = hv;
            hl0 = h0; hl1 = h1;
        }
        xv0 = xn0; xv1 = xn1; xv2 = xn2; xv3 = xn3;
        __syncthreads();                                  // B3: own half visible
    }

    if (tid < 64) {
        float2 hv; hv.x = hl0; hv.y = hl1;
        *(float2*)(OUT + (size_t)BATCH * TSEQ * HID + (size_t)pair * HID
                   + pbase + 2 * tid) = hv;
    }
}

extern "C" void kernel_launch(void* const* d_in, const int* in_sizes, int n_in,
                              void* d_out, int out_size, void* d_ws, size_t ws_size,
                              hipStream_t stream) {
    const float* x  = (const float*)d_in[0];
    const float* wx = (const float*)d_in[1];
    const float* wh = (const float*)d_in[2];
    const float* bx = (const float*)d_in[3];
    const float* bh = (const float*)d_in[4];
    float* out = (float*)d_out;

    // workspace: [xp fp16: 256 MB][WS: 32768 uint4 = 512 KB][EXD: 16384 u32][SEQ: 4096 u32]
    _Float16* xp = (_Float16*)d_ws;
    uint4* ws = (uint4*)((char*)d_ws + (size_t)BATCH * TSEQ * G4 * sizeof(_Float16));
    unsigned* exd = (unsigned*)(ws + 32768);
    unsigned* seq = exd + 16384;

    hipLaunchKernelGGL(wt_convert, dim3(128), dim3(256), 0, stream, wh, ws, seq);
    hipLaunchKernelGGL(xproj_gemm, dim3(G4 / 64, (BATCH * TSEQ) / 64), dim3(256), 0, stream,
                       x, wx, bx, bh, xp);
    hipLaunchKernelGGL(lstm_rec, dim3(2 * BATCH), dim3(512), 0, stream, xp, ws, exd, seq, out);
}